// Round 7
// baseline (417.663 us; speedup 1.0000x reference)
//
#include <hip/hip_runtime.h>
#include <hip/hip_bf16.h>
#include <math.h>

// Problem dims (fixed by reference setup_inputs)
#define T_TOK   2048
#define DDIM    1024
#define FDIM    4096
#define NEXP    8
#define MAXROWS 4608

typedef __bf16          bf16x8 __attribute__((ext_vector_type(8)));
typedef float           f32x4  __attribute__((ext_vector_type(4)));
typedef unsigned short  u16x8  __attribute__((ext_vector_type(8)));

#define LDSP 40   // legacy-path padded LDS stride
#define FCW  128

static __device__ __forceinline__ unsigned short f2b(float f) {
    __hip_bfloat16 h = __float2bfloat16(f);   // RNE
    return __builtin_bit_cast(unsigned short, h);
}

// async global->LDS, 16B per lane (dest must be linear: base + lane*16)
static __device__ __forceinline__ void gll16(const unsigned short* g, unsigned short* l) {
    __builtin_amdgcn_global_load_lds(
        (const __attribute__((address_space(1))) unsigned int*)g,
        (__attribute__((address_space(3))) unsigned int*)l, 16, 0, 0);
}

// ---------------------------------------------------------------- router
__global__ __launch_bounds__(256) void moe_router_kernel(
    const float* __restrict__ x, const float* __restrict__ gate_w,
    float* __restrict__ logits_out, int* __restrict__ top_e, float* __restrict__ top_w)
{
    int wid  = (blockIdx.x * blockDim.x + threadIdx.x) >> 6;   // token id (one wave/token)
    int lane = threadIdx.x & 63;
    if (wid >= T_TOK) return;
    const float* xr = x + (size_t)wid * DDIM;
    float acc[NEXP];
    #pragma unroll
    for (int e = 0; e < NEXP; ++e) acc[e] = 0.f;
    for (int d = lane; d < DDIM; d += 64) {
        float xv = xr[d];
        #pragma unroll
        for (int e = 0; e < NEXP; ++e) acc[e] += xv * gate_w[e * DDIM + d];
    }
    #pragma unroll
    for (int e = 0; e < NEXP; ++e) {
        #pragma unroll
        for (int off = 32; off > 0; off >>= 1)
            acc[e] += __shfl_down(acc[e], off, 64);
    }
    if (lane == 0) {
        #pragma unroll
        for (int e = 0; e < NEXP; ++e) logits_out[wid * NEXP + e] = acc[e];
        int e1 = 0;
        #pragma unroll
        for (int e = 1; e < NEXP; ++e) if (acc[e] > acc[e1]) e1 = e;   // strict > keeps lowest idx
        int e2 = (e1 == 0) ? 1 : 0;
        #pragma unroll
        for (int e = 0; e < NEXP; ++e) if (e != e1 && acc[e] > acc[e2]) e2 = e;
        float p2 = __expf(acc[e2] - acc[e1]);   // acc[e1] is global max
        float s  = 1.0f + p2;
        top_e[wid * 2]     = e1;
        top_e[wid * 2 + 1] = e2;
        top_w[wid * 2]     = 1.0f / s;
        top_w[wid * 2 + 1] = p2 / s;
    }
}

// ---------------------------------------------------------------- scatter
__global__ void moe_scatter_kernel(const int* __restrict__ top_e, const float* __restrict__ top_w,
                                   int* __restrict__ cnt, int* __restrict__ list_tok,
                                   float* __restrict__ list_w)
{
    int t = blockIdx.x * blockDim.x + threadIdx.x;
    if (t >= T_TOK) return;
    #pragma unroll
    for (int s = 0; s < 2; ++s) {
        int e   = top_e[t * 2 + s];
        int pos = atomicAdd(&cnt[e], 1);
        list_tok[e * T_TOK + pos] = t;
        list_w [e * T_TOK + pos] = top_w[t * 2 + s];
    }
}

// ---------------------------------------------------------------- prefix offsets (rows padded to 64)
__global__ void moe_prefix_kernel(const int* __restrict__ cnt, int* __restrict__ offs)
{
    if (threadIdx.x == 0 && blockIdx.x == 0) {
        int o = 0;
        #pragma unroll
        for (int e = 0; e < NEXP; ++e) { offs[e] = o; o += ((cnt[e] + 63) >> 6) << 6; }
        offs[NEXP] = o;
    }
}

// ---------------------------------------------------------------- weight transpose+convert: fp32 [E][R][C] -> bf16 [E][C][R]
__global__ __launch_bounds__(256) void transpose_cvt2_kernel(
    const float* __restrict__ srcA, unsigned short* __restrict__ dstA,
    const float* __restrict__ srcB, unsigned short* __restrict__ dstB, int R, int C)
{
    int tilesC = C >> 6;
    int tilesPerMat = (R >> 6) * tilesC;
    int e  = blockIdx.x / tilesPerMat;
    int t  = blockIdx.x - e * tilesPerMat;
    int tr = t / tilesC, tc = t - tr * tilesC;
    size_t soff = (size_t)e * R * C + (size_t)(tr * 64) * C + tc * 64;
    size_t doff = (size_t)e * R * C + (size_t)(tc * 64) * R + tr * 64;

    __shared__ unsigned short lds[64][72];
    int tid = threadIdx.x;
    int rr = tid >> 4, cc = (tid & 15) * 4;
    int orow = tid >> 2, oc = (tid & 3) * 16;

    #pragma unroll
    for (int m = 0; m < 2; ++m) {
        const float*    s = (m == 0 ? srcA : srcB) + soff;
        unsigned short* d = (m == 0 ? dstA : dstB) + doff;
        if (m) __syncthreads();
        #pragma unroll
        for (int i = 0; i < 4; ++i) {
            int r = rr + 16 * i;
            float4 v = *(const float4*)(s + (size_t)r * C + cc);
            lds[cc + 0][r] = f2b(v.x); lds[cc + 1][r] = f2b(v.y);
            lds[cc + 2][r] = f2b(v.z); lds[cc + 3][r] = f2b(v.w);
        }
        __syncthreads();
        u16x8 a = *(const u16x8*)&lds[orow][oc];
        u16x8 b = *(const u16x8*)&lds[orow][oc + 8];
        *(u16x8*)(d + (size_t)orow * R + oc)     = a;
        *(u16x8*)(d + (size_t)orow * R + oc + 8) = b;
    }
}

__global__ __launch_bounds__(256) void transpose_cvt_kernel(
    const float* __restrict__ src, unsigned short* __restrict__ dst, int R, int C)
{
    int tilesC = C >> 6;
    int tilesPerMat = (R >> 6) * tilesC;
    int e  = blockIdx.x / tilesPerMat;
    int t  = blockIdx.x - e * tilesPerMat;
    int tr = t / tilesC, tc = t - tr * tilesC;
    const float*    s = src + (size_t)e * R * C + (size_t)(tr * 64) * C + tc * 64;
    unsigned short* d = dst + (size_t)e * R * C + (size_t)(tc * 64) * R + tr * 64;

    __shared__ unsigned short lds[64][72];
    int tid = threadIdx.x;
    int rr = tid >> 4, cc = (tid & 15) * 4;
    #pragma unroll
    for (int i = 0; i < 4; ++i) {
        int r = rr + 16 * i;
        float4 v = *(const float4*)(s + (size_t)r * C + cc);
        lds[cc + 0][r] = f2b(v.x); lds[cc + 1][r] = f2b(v.y);
        lds[cc + 2][r] = f2b(v.z); lds[cc + 3][r] = f2b(v.w);
    }
    __syncthreads();
    int orow = tid >> 2, oc = (tid & 3) * 16;
    u16x8 a = *(const u16x8*)&lds[orow][oc];
    u16x8 b = *(const u16x8*)&lds[orow][oc + 8];
    *(u16x8*)(d + (size_t)orow * R + oc)     = a;
    *(u16x8*)(d + (size_t)orow * R + oc + 8) = b;
}

// ---------------------------------------------------------------- gather+convert token rows -> xg bf16 [slot][D]
__global__ __launch_bounds__(256) void moe_gather_kernel(
    const float* __restrict__ x, const int* __restrict__ list_tok,
    const int* __restrict__ cnt, const int* __restrict__ offs,
    unsigned short* __restrict__ xg)
{
    int e  = blockIdx.x >> 8;
    int rb = blockIdx.x & 255;
    int n = cnt[e];
    int npad = (n + 63) & ~63;
    if (rb * 8 >= npad) return;
    int base = offs[e];
    int tid = threadIdx.x;
    #pragma unroll
    for (int i = 0; i < 4; ++i) {
        int u = tid + 256 * i;
        int r = u >> 7, cu = u & 127;
        int slot = rb * 8 + r;
        int tok = list_tok[e * T_TOK + slot];
        const float* sp = x + (size_t)tok * DDIM + cu * 8;
        float4 v0 = *(const float4*)(sp);
        float4 v1 = *(const float4*)(sp + 4);
        u16x8 t8;
        t8[0]=f2b(v0.x); t8[1]=f2b(v0.y); t8[2]=f2b(v0.z); t8[3]=f2b(v0.w);
        t8[4]=f2b(v1.x); t8[5]=f2b(v1.y); t8[6]=f2b(v1.z); t8[7]=f2b(v1.w);
        *(u16x8*)(xg + (size_t)(base + slot) * DDIM + cu * 8) = t8;
    }
}

// ---------------------------------------------------------------- expert up, 2-phase prefetch dbuf
// bid = [idx(9b) | xcd(3b)]; e = xcd; idx = mt*32 + fc, mt slowest (active blocks first).
// launch_bounds (256,2): acc needs 128 regs; tighter bound spills (round-5 lesson).
__global__ __launch_bounds__(256, 2) void moe_up_kernel(
    const unsigned short* __restrict__ xg,
    const unsigned short* __restrict__ w1t, const unsigned short* __restrict__ w3t,
    const int* __restrict__ cnt, const int* __restrict__ offs,
    unsigned short* __restrict__ act)
{
    int e   = blockIdx.x & 7;
    int idx = blockIdx.x >> 3;      // 0..511
    int mt  = idx >> 5;             // 0..15 (slowest -> active first)
    int fc  = idx & 31;
    int n = cnt[e];
    int npad = (n + 63) & ~63;
    if (mt * 128 >= npad) return;
    int rowBase  = offs[e] + mt * 128;
    int rowMax   = offs[e] + npad - 1;
    int rowLimit = offs[e] + npad;

    __shared__ unsigned short As [2][128 * 32];   // linear [row][k], double-buffered
    __shared__ unsigned short B1s[2][128 * 32];
    __shared__ unsigned short B2s[2][128 * 32];

    int tid = threadIdx.x;
    int lane = tid & 63, wv = tid >> 6;
    int c = lane & 15, g = lane >> 4;
    int wr = (wv >> 1) * 64, wc = (wv & 1) * 64;

    int srow = tid >> 2, skc = tid & 3;
    int r0 = min(rowBase + srow,      rowMax);
    int r1 = min(rowBase + 64 + srow, rowMax);
    const unsigned short* gA0 = xg + (size_t)r0 * DDIM + skc * 8;
    const unsigned short* gA1 = xg + (size_t)r1 * DDIM + skc * 8;
    size_t wb = (size_t)e * FDIM * DDIM + (size_t)(fc * 128 + srow) * DDIM + skc * 8;
    const unsigned short* gB1a = w1t + wb;
    const unsigned short* gB1b = w1t + wb + (size_t)64 * DDIM;
    const unsigned short* gB2a = w3t + wb;
    const unsigned short* gB2b = w3t + wb + (size_t)64 * DDIM;

    auto STAGE = [&](int buf, int k0) {
        gll16(gA0  + k0, &As [buf][tid * 8]);
        gll16(gA1  + k0, &As [buf][2048 + tid * 8]);
        gll16(gB1a + k0, &B1s[buf][tid * 8]);
        gll16(gB1b + k0, &B1s[buf][2048 + tid * 8]);
        gll16(gB2a + k0, &B2s[buf][tid * 8]);
        gll16(gB2b + k0, &B2s[buf][2048 + tid * 8]);
    };

    f32x4 acc_h[4][4], acc_g[4][4];
    #pragma unroll
    for (int i = 0; i < 4; ++i)
        #pragma unroll
        for (int j = 0; j < 4; ++j) { acc_h[i][j] = (f32x4)(0.f); acc_g[i][j] = (f32x4)(0.f); }

    STAGE(0, 0);
    __syncthreads();                 // prologue: tile 0 resident

    for (int t = 0; t < 32; ++t) {
        int cur = t & 1;
        if (t < 31) STAGE(cur ^ 1, (t + 1) * 32);   // async prefetch overlaps compute

        bf16x8 af[4];
        #pragma unroll
        for (int mi = 0; mi < 4; ++mi)
            af[mi] = *reinterpret_cast<const bf16x8*>(&As[cur][(wr + mi * 16 + c) * 32 + g * 8]);
        #pragma unroll
        for (int ni = 0; ni < 4; ++ni) {
            bf16x8 b1 = *reinterpret_cast<const bf16x8*>(&B1s[cur][(wc + ni * 16 + c) * 32 + g * 8]);
            bf16x8 b2 = *reinterpret_cast<const bf16x8*>(&B2s[cur][(wc + ni * 16 + c) * 32 + g * 8]);
            #pragma unroll
            for (int mi = 0; mi < 4; ++mi) {
                acc_h[mi][ni] = __builtin_amdgcn_mfma_f32_16x16x32_bf16(af[mi], b1, acc_h[mi][ni], 0, 0, 0);
                acc_g[mi][ni] = __builtin_amdgcn_mfma_f32_16x16x32_bf16(af[mi], b2, acc_g[mi][ni], 0, 0, 0);
            }
        }
        __syncthreads();             // drains vmcnt: prefetched tile landed; buf[cur] free
    }

    #pragma unroll
    for (int mi = 0; mi < 4; ++mi) {
        int row = rowBase + wr + mi * 16 + 4 * g;
        if (row < rowLimit) {
            #pragma unroll
            for (int ni = 0; ni < 4; ++ni) {
                int col = fc * 128 + wc + ni * 16 + c;
                #pragma unroll
                for (int r = 0; r < 4; ++r) {
                    float h  = acc_h[mi][ni][r];
                    float gg = acc_g[mi][ni][r];
                    float a  = h / (1.f + __expf(-h)) * gg;
                    act[(size_t)(row + r) * FDIM + col] = f2b(a);
                }
            }
        }
    }
}

// ---------------------------------------------------------------- expert down, 2-phase prefetch dbuf
// bid = [idx(9b) | xcd(3b)]; e = xcd; idx = mt*32 + ks*8 + dc, mt slowest.
__global__ __launch_bounds__(256, 3) void moe_down_kernel(
    const unsigned short* __restrict__ act, const unsigned short* __restrict__ w2t,
    const int* __restrict__ cnt, const int* __restrict__ offs,
    const int* __restrict__ list_tok, const float* __restrict__ list_w,
    float* __restrict__ out)
{
    int e   = blockIdx.x & 7;
    int idx = blockIdx.x >> 3;      // 0..511
    int mt  = idx >> 5;             // slowest
    int ks  = (idx >> 3) & 3;
    int dc  = idx & 7;
    int n = cnt[e];
    int npad = (n + 63) & ~63;
    if (mt * 128 >= npad) return;
    int rowBase = offs[e] + mt * 128;
    int rowMax  = offs[e] + npad - 1;

    __shared__ unsigned short As[2][128 * 32];
    __shared__ unsigned short Bs[2][128 * 32];

    int tid = threadIdx.x;
    int lane = tid & 63, wv = tid >> 6;
    int c = lane & 15, g = lane >> 4;
    int wr = (wv >> 1) * 64, wc = (wv & 1) * 64;

    int srow = tid >> 2, skc = tid & 3;
    int r0 = min(rowBase + srow,      rowMax);
    int r1 = min(rowBase + 64 + srow, rowMax);
    const unsigned short* gA0 = act + (size_t)r0 * FDIM + ks * 1024 + skc * 8;
    const unsigned short* gA1 = act + (size_t)r1 * FDIM + ks * 1024 + skc * 8;
    size_t wb = (size_t)e * DDIM * FDIM + (size_t)(dc * 128 + srow) * FDIM + ks * 1024 + skc * 8;
    const unsigned short* gBa = w2t + wb;
    const unsigned short* gBb = w2t + wb + (size_t)64 * FDIM;

    auto STAGE = [&](int buf, int k0) {
        gll16(gA0 + k0, &As[buf][tid * 8]);
        gll16(gA1 + k0, &As[buf][2048 + tid * 8]);
        gll16(gBa + k0, &Bs[buf][tid * 8]);
        gll16(gBb + k0, &Bs[buf][2048 + tid * 8]);
    };

    f32x4 acc[4][4];
    #pragma unroll
    for (int i = 0; i < 4; ++i)
        #pragma unroll
        for (int j = 0; j < 4; ++j) acc[i][j] = (f32x4)(0.f);

    STAGE(0, 0);
    __syncthreads();

    for (int t = 0; t < 32; ++t) {
        int cur = t & 1;
        if (t < 31) STAGE(cur ^ 1, (t + 1) * 32);

        bf16x8 af[4];
        #pragma unroll
        for (int mi = 0; mi < 4; ++mi)
            af[mi] = *reinterpret_cast<const bf16x8*>(&As[cur][(wr + mi * 16 + c) * 32 + g * 8]);
        #pragma unroll
        for (int ni = 0; ni < 4; ++ni) {
            bf16x8 b = *reinterpret_cast<const bf16x8*>(&Bs[cur][(wc + ni * 16 + c) * 32 + g * 8]);
            #pragma unroll
            for (int mi = 0; mi < 4; ++mi)
                acc[mi][ni] = __builtin_amdgcn_mfma_f32_16x16x32_bf16(af[mi], b, acc[mi][ni], 0, 0, 0);
        }
        __syncthreads();
    }

    #pragma unroll
    for (int mi = 0; mi < 4; ++mi) {
        #pragma unroll
        for (int r = 0; r < 4; ++r) {
            int s = mt * 128 + wr + mi * 16 + 4 * g + r;
            if (s < n) {
                int   tok = list_tok[e * T_TOK + s];
                float wt  = list_w [e * T_TOK + s];
                #pragma unroll
                for (int ni = 0; ni < 4; ++ni) {
                    int col = dc * 128 + wc + ni * 16 + c;
                    atomicAdd(&out[(size_t)tok * DDIM + col], wt * acc[mi][ni][r]);
                }
            }
        }
    }
}

// ================================================================ legacy fp32-weight path (ws too small)
__global__ __launch_bounds__(256, 3) void moe_up_legacy(
    const float* __restrict__ x, const float* __restrict__ w1, const float* __restrict__ w3,
    const int* __restrict__ cnt, const int* __restrict__ offs,
    const int* __restrict__ list_tok, unsigned short* __restrict__ act)
{
    const int NWG = NEXP * 32 * 32;
    int bid     = blockIdx.x;
    int logical = (bid & 7) * (NWG >> 3) + (bid >> 3);
    int tile = logical & 31;
    int fc   = (logical >> 5) & 31;
    int e    = logical >> 10;
    int n = cnt[e];
    if (tile * 64 >= n) return;

    __shared__ unsigned short As [64  * LDSP];
    __shared__ unsigned short B1s[FCW * LDSP];
    __shared__ unsigned short B2s[FCW * LDSP];

    int tid = threadIdx.x;
    int lane = tid & 63, wv = tid >> 6;
    int c = lane & 15, g = lane >> 4;
    int ar = tid >> 2, akq = tid & 3;
    int tok = list_tok[e * T_TOK + tile * 64 + ar];
    const float* xrow = x + (size_t)tok * DDIM + akq * 8;
    int bcol = tid & 127, bkh = tid >> 7;
    const size_t wbase = (size_t)e * DDIM * FDIM + (size_t)fc * FCW + bcol;
    const float* w1c = w1 + wbase;
    const float* w3c = w3 + wbase;

    f32x4 acc_h[4][2], acc_g[4][2];
    #pragma unroll
    for (int i = 0; i < 4; ++i)
        #pragma unroll
        for (int j = 0; j < 2; ++j) { acc_h[i][j] = (f32x4)(0.f); acc_g[i][j] = (f32x4)(0.f); }

    for (int k0 = 0; k0 < DDIM; k0 += 32) {
        {
            const float4 v0 = *(const float4*)(xrow + k0);
            const float4 v1 = *(const float4*)(xrow + k0 + 4);
            u16x8 t8;
            t8[0]=f2b(v0.x); t8[1]=f2b(v0.y); t8[2]=f2b(v0.z); t8[3]=f2b(v0.w);
            t8[4]=f2b(v1.x); t8[5]=f2b(v1.y); t8[6]=f2b(v1.z); t8[7]=f2b(v1.w);
            *reinterpret_cast<u16x8*>(&As[ar * LDSP + akq * 8]) = t8;
        }
        {
            int kb = k0 + bkh * 16;
            u16x8 t1a, t1b, t2a, t2b;
            #pragma unroll
            for (int j = 0; j < 8; ++j) {
                t1a[j] = f2b(w1c[(size_t)(kb + j)     * FDIM]);
                t1b[j] = f2b(w1c[(size_t)(kb + 8 + j) * FDIM]);
                t2a[j] = f2b(w3c[(size_t)(kb + j)     * FDIM]);
                t2b[j] = f2b(w3c[(size_t)(kb + 8 + j) * FDIM]);
            }
            *reinterpret_cast<u16x8*>(&B1s[bcol * LDSP + bkh * 16])     = t1a;
            *reinterpret_cast<u16x8*>(&B1s[bcol * LDSP + bkh * 16 + 8]) = t1b;
            *reinterpret_cast<u16x8*>(&B2s[bcol * LDSP + bkh * 16])     = t2a;
            *reinterpret_cast<u16x8*>(&B2s[bcol * LDSP + bkh * 16 + 8]) = t2b;
        }
        __syncthreads();
        bf16x8 af[4];
        #pragma unroll
        for (int mi = 0; mi < 4; ++mi)
            af[mi] = *reinterpret_cast<const bf16x8*>(&As[(mi * 16 + c) * LDSP + g * 8]);
        #pragma unroll
        for (int ni = 0; ni < 2; ++ni) {
            int col = wv * 32 + ni * 16 + c;
            bf16x8 b1 = *reinterpret_cast<const bf16x8*>(&B1s[col * LDSP + g * 8]);
            bf16x8 b2 = *reinterpret_cast<const bf16x8*>(&B2s[col * LDSP + g * 8]);
            #pragma unroll
            for (int mi = 0; mi < 4; ++mi) {
                acc_h[mi][ni] = __builtin_amdgcn_mfma_f32_16x16x32_bf16(af[mi], b1, acc_h[mi][ni], 0, 0, 0);
                acc_g[mi][ni] = __builtin_amdgcn_mfma_f32_16x16x32_bf16(af[mi], b2, acc_g[mi][ni], 0, 0, 0);
            }
        }
        __syncthreads();
    }
    int rowBase = offs[e] + tile * 64;
    #pragma unroll
    for (int mi = 0; mi < 4; ++mi)
        #pragma unroll
        for (int ni = 0; ni < 2; ++ni)
            #pragma unroll
            for (int r = 0; r < 4; ++r) {
                float h  = acc_h[mi][ni][r];
                float gg = acc_g[mi][ni][r];
                float a  = h / (1.f + __expf(-h)) * gg;
                int row = rowBase + mi * 16 + 4 * g + r;
                int col = fc * FCW + wv * 32 + ni * 16 + c;
                act[(size_t)row * FDIM + col] = f2b(a);
            }
}

__global__ __launch_bounds__(256, 3) void moe_down_legacy(
    const unsigned short* __restrict__ act, const float* __restrict__ w2,
    const int* __restrict__ cnt, const int* __restrict__ offs,
    const int* __restrict__ list_tok, const float* __restrict__ list_w,
    float* __restrict__ out)
{
    const int NWG = NEXP * 4 * 4 * 32;
    int bid     = blockIdx.x;
    int logical = (bid & 7) * (NWG >> 3) + (bid >> 3);
    int tile = logical & 31;
    int ks   = (logical >> 5) & 3;
    int dc   = (logical >> 7) & 3;
    int e    = logical >> 9;
    int n = cnt[e];
    if (tile * 64 >= n) return;

    __shared__ unsigned short As[64  * LDSP];
    __shared__ unsigned short Bs[256 * LDSP];
    int tid = threadIdx.x;
    int lane = tid & 63, wv = tid >> 6;
    int c = lane & 15, g = lane >> 4;
    int rowBase = offs[e] + tile * 64;
    int ar = tid >> 2, akq = tid & 3;
    const unsigned short* arow = act + (size_t)(rowBase + ar) * FDIM + ks * 1024 + akq * 8;
    const float* w2c = w2 + (size_t)e * FDIM * DDIM + (size_t)(ks * 1024) * DDIM + (size_t)dc * 256 + tid;

    f32x4 acc[4][4];
    #pragma unroll
    for (int i = 0; i < 4; ++i)
        #pragma unroll
        for (int j = 0; j < 4; ++j) acc[i][j] = (f32x4)(0.f);

    for (int k0 = 0; k0 < 1024; k0 += 32) {
        *reinterpret_cast<u16x8*>(&As[ar * LDSP + akq * 8]) = *reinterpret_cast<const u16x8*>(arow + k0);
        #pragma unroll
        for (int kk = 0; kk < 4; ++kk) {
            u16x8 t1;
            #pragma unroll
            for (int j = 0; j < 8; ++j)
                t1[j] = f2b(w2c[(size_t)(k0 + kk * 8 + j) * DDIM]);
            *reinterpret_cast<u16x8*>(&Bs[tid * LDSP + kk * 8]) = t1;
        }
        __syncthreads();
        bf16x8 af[4];
        #pragma unroll
        for (int mi = 0; mi < 4; ++mi)
            af[mi] = *reinterpret_cast<const bf16x8*>(&As[(mi * 16 + c) * LDSP + g * 8]);
        #pragma unroll
        for (int ni = 0; ni < 4; ++ni) {
            bf16x8 b = *reinterpret_cast<const bf16x8*>(&Bs[(wv * 64 + ni * 16 + c) * LDSP + g * 8]);
            #pragma unroll
            for (int mi = 0; mi < 4; ++mi)
                acc[mi][ni] = __builtin_amdgcn_mfma_f32_16x16x32_bf16(af[mi], b, acc[mi][ni], 0, 0, 0);
        }
        __syncthreads();
    }
    #pragma unroll
    for (int mi = 0; mi < 4; ++mi)
        #pragma unroll
        for (int r = 0; r < 4; ++r) {
            int s = tile * 64 + mi * 16 + 4 * g + r;
            if (s < n) {
                int   tok = list_tok[e * T_TOK + s];
                float wt  = list_w [e * T_TOK + s];
                #pragma unroll
                for (int ni = 0; ni < 4; ++ni) {
                    int col = dc * 256 + wv * 64 + ni * 16 + c;
                    atomicAdd(&out[(size_t)tok * DDIM + col], wt * acc[mi][ni][r]);
                }
            }
        }
}

// ---------------------------------------------------------------- launch
extern "C" void kernel_launch(void* const* d_in, const int* in_sizes, int n_in,
                              void* d_out, int out_size, void* d_ws, size_t ws_size,
                              hipStream_t stream) {
    const float* x      = (const float*)d_in[0];
    const float* gate_w = (const float*)d_in[1];
    const float* w1     = (const float*)d_in[2];
    const float* w2     = (const float*)d_in[3];
    const float* w3     = (const float*)d_in[4];
    float* out        = (float*)d_out;
    float* logits_out = out + (size_t)T_TOK * DDIM;

    char* ws = (char*)d_ws;
    int*   cnt      = (int*)  (ws);
    int*   offs     = (int*)  (ws + 64);
    int*   top_e    = (int*)  (ws + 1024);
    float* top_w    = (float*)(ws + 17408);
    int*   list_tok = (int*)  (ws + 33792);
    float* list_w   = (float*)(ws + 99328);

    hipMemsetAsync(cnt, 0, 64, stream);
    hipMemsetAsync(list_tok, 0, 131072, stream);   // list_tok + list_w
    hipMemsetAsync(out, 0, (size_t)T_TOK * DDIM * sizeof(float), stream);

    moe_router_kernel <<<T_TOK / 4,   256, 0, stream>>>(x, gate_w, logits_out, top_e, top_w);
    moe_scatter_kernel<<<T_TOK / 256, 256, 0, stream>>>(top_e, top_w, cnt, list_tok, list_w);
    moe_prefix_kernel <<<1, 64, 0, stream>>>(cnt, offs);

    const size_t MB = 1u << 20;
    const size_t NEED = 241 * MB;
    if (ws_size >= NEED) {
        unsigned short* xg  = (unsigned short*)(ws + 1   * MB);   //  9.44 MB
        unsigned short* act = (unsigned short*)(ws + 11  * MB);   // 37.75 MB
        unsigned short* w1t = (unsigned short*)(ws + 49  * MB);   // 64 MB  [E][F][D]
        unsigned short* w3t = (unsigned short*)(ws + 113 * MB);   // 64 MB  [E][F][D]
        unsigned short* w2t = (unsigned short*)(ws + 177 * MB);   // 64 MB  [E][D][F]

        moe_gather_kernel<<<NEXP * 256, 256, 0, stream>>>(x, list_tok, cnt, offs, xg);
        transpose_cvt2_kernel<<<NEXP * 16 * 64, 256, 0, stream>>>(w1, w1t, w3, w3t, DDIM, FDIM);
        transpose_cvt_kernel <<<NEXP * 64 * 16, 256, 0, stream>>>(w2, w2t, FDIM, DDIM);

        moe_up_kernel   <<<NEXP * 16 * 32, 256, 0, stream>>>(xg, w1t, w3t, cnt, offs, act);
        moe_down_kernel <<<NEXP * 16 * 32, 256, 0, stream>>>(act, w2t, cnt, offs, list_tok, list_w, out);
    } else {
        unsigned short* act = (unsigned short*)(ws + 164864);
        moe_up_legacy   <<<NEXP * 32 * 32,    256, 0, stream>>>(x, w1, w3, cnt, offs, list_tok, act);
        moe_down_legacy <<<NEXP * 4 * 4 * 32, 256, 0, stream>>>(act, w2, cnt, offs, list_tok, list_w, out);
    }
}

// Round 8
// 355.655 us; speedup vs baseline: 1.1743x; 1.1743x over previous
//
#include <hip/hip_runtime.h>
#include <hip/hip_bf16.h>
#include <math.h>

// Problem dims (fixed by reference setup_inputs)
#define T_TOK   2048
#define DDIM    1024
#define FDIM    4096
#define NEXP    8
#define MAXROWS 4608

typedef __bf16          bf16x8 __attribute__((ext_vector_type(8)));
typedef float           f32x4  __attribute__((ext_vector_type(4)));
typedef unsigned short  u16x8  __attribute__((ext_vector_type(8)));

#define LDSP 40   // legacy-path padded LDS stride
#define FCW  128

static __device__ __forceinline__ unsigned short f2b(float f) {
    __hip_bfloat16 h = __float2bfloat16(f);   // RNE
    return __builtin_bit_cast(unsigned short, h);
}

// async global->LDS, 16B per lane (dest must be linear: base + lane*16)
static __device__ __forceinline__ void gll16(const unsigned short* g, unsigned short* l) {
    __builtin_amdgcn_global_load_lds(
        (const __attribute__((address_space(1))) unsigned int*)g,
        (__attribute__((address_space(3))) unsigned int*)l, 16, 0, 0);
}

// ---------------------------------------------------------------- router
__global__ __launch_bounds__(256) void moe_router_kernel(
    const float* __restrict__ x, const float* __restrict__ gate_w,
    float* __restrict__ logits_out, int* __restrict__ top_e, float* __restrict__ top_w)
{
    int wid  = (blockIdx.x * blockDim.x + threadIdx.x) >> 6;   // token id (one wave/token)
    int lane = threadIdx.x & 63;
    if (wid >= T_TOK) return;
    const float* xr = x + (size_t)wid * DDIM;
    float acc[NEXP];
    #pragma unroll
    for (int e = 0; e < NEXP; ++e) acc[e] = 0.f;
    for (int d = lane; d < DDIM; d += 64) {
        float xv = xr[d];
        #pragma unroll
        for (int e = 0; e < NEXP; ++e) acc[e] += xv * gate_w[e * DDIM + d];
    }
    #pragma unroll
    for (int e = 0; e < NEXP; ++e) {
        #pragma unroll
        for (int off = 32; off > 0; off >>= 1)
            acc[e] += __shfl_down(acc[e], off, 64);
    }
    if (lane == 0) {
        #pragma unroll
        for (int e = 0; e < NEXP; ++e) logits_out[wid * NEXP + e] = acc[e];
        int e1 = 0;
        #pragma unroll
        for (int e = 1; e < NEXP; ++e) if (acc[e] > acc[e1]) e1 = e;   // strict > keeps lowest idx
        int e2 = (e1 == 0) ? 1 : 0;
        #pragma unroll
        for (int e = 0; e < NEXP; ++e) if (e != e1 && acc[e] > acc[e2]) e2 = e;
        float p2 = __expf(acc[e2] - acc[e1]);   // acc[e1] is global max
        float s  = 1.0f + p2;
        top_e[wid * 2]     = e1;
        top_e[wid * 2 + 1] = e2;
        top_w[wid * 2]     = 1.0f / s;
        top_w[wid * 2 + 1] = p2 / s;
    }
}

// ---------------------------------------------------------------- scatter
__global__ void moe_scatter_kernel(const int* __restrict__ top_e, const float* __restrict__ top_w,
                                   int* __restrict__ cnt, int* __restrict__ list_tok,
                                   float* __restrict__ list_w)
{
    int t = blockIdx.x * blockDim.x + threadIdx.x;
    if (t >= T_TOK) return;
    #pragma unroll
    for (int s = 0; s < 2; ++s) {
        int e   = top_e[t * 2 + s];
        int pos = atomicAdd(&cnt[e], 1);
        list_tok[e * T_TOK + pos] = t;
        list_w [e * T_TOK + pos] = top_w[t * 2 + s];
    }
}

// ---------------------------------------------------------------- prefix offsets (rows padded to 64)
__global__ void moe_prefix_kernel(const int* __restrict__ cnt, int* __restrict__ offs)
{
    if (threadIdx.x == 0 && blockIdx.x == 0) {
        int o = 0;
        #pragma unroll
        for (int e = 0; e < NEXP; ++e) { offs[e] = o; o += ((cnt[e] + 63) >> 6) << 6; }
        offs[NEXP] = o;
    }
}

// ---------------------------------------------------------------- weight transpose+convert: fp32 [E][R][C] -> bf16 [E][C][R]
__global__ __launch_bounds__(256) void transpose_cvt2_kernel(
    const float* __restrict__ srcA, unsigned short* __restrict__ dstA,
    const float* __restrict__ srcB, unsigned short* __restrict__ dstB, int R, int C)
{
    int tilesC = C >> 6;
    int tilesPerMat = (R >> 6) * tilesC;
    int e  = blockIdx.x / tilesPerMat;
    int t  = blockIdx.x - e * tilesPerMat;
    int tr = t / tilesC, tc = t - tr * tilesC;
    size_t soff = (size_t)e * R * C + (size_t)(tr * 64) * C + tc * 64;
    size_t doff = (size_t)e * R * C + (size_t)(tc * 64) * R + tr * 64;

    __shared__ unsigned short lds[64][72];
    int tid = threadIdx.x;
    int rr = tid >> 4, cc = (tid & 15) * 4;
    int orow = tid >> 2, oc = (tid & 3) * 16;

    #pragma unroll
    for (int m = 0; m < 2; ++m) {
        const float*    s = (m == 0 ? srcA : srcB) + soff;
        unsigned short* d = (m == 0 ? dstA : dstB) + doff;
        if (m) __syncthreads();
        #pragma unroll
        for (int i = 0; i < 4; ++i) {
            int r = rr + 16 * i;
            float4 v = *(const float4*)(s + (size_t)r * C + cc);
            lds[cc + 0][r] = f2b(v.x); lds[cc + 1][r] = f2b(v.y);
            lds[cc + 2][r] = f2b(v.z); lds[cc + 3][r] = f2b(v.w);
        }
        __syncthreads();
        u16x8 a = *(const u16x8*)&lds[orow][oc];
        u16x8 b = *(const u16x8*)&lds[orow][oc + 8];
        *(u16x8*)(d + (size_t)orow * R + oc)     = a;
        *(u16x8*)(d + (size_t)orow * R + oc + 8) = b;
    }
}

__global__ __launch_bounds__(256) void transpose_cvt_kernel(
    const float* __restrict__ src, unsigned short* __restrict__ dst, int R, int C)
{
    int tilesC = C >> 6;
    int tilesPerMat = (R >> 6) * tilesC;
    int e  = blockIdx.x / tilesPerMat;
    int t  = blockIdx.x - e * tilesPerMat;
    int tr = t / tilesC, tc = t - tr * tilesC;
    const float*    s = src + (size_t)e * R * C + (size_t)(tr * 64) * C + tc * 64;
    unsigned short* d = dst + (size_t)e * R * C + (size_t)(tc * 64) * R + tr * 64;

    __shared__ unsigned short lds[64][72];
    int tid = threadIdx.x;
    int rr = tid >> 4, cc = (tid & 15) * 4;
    #pragma unroll
    for (int i = 0; i < 4; ++i) {
        int r = rr + 16 * i;
        float4 v = *(const float4*)(s + (size_t)r * C + cc);
        lds[cc + 0][r] = f2b(v.x); lds[cc + 1][r] = f2b(v.y);
        lds[cc + 2][r] = f2b(v.z); lds[cc + 3][r] = f2b(v.w);
    }
    __syncthreads();
    int orow = tid >> 2, oc = (tid & 3) * 16;
    u16x8 a = *(const u16x8*)&lds[orow][oc];
    u16x8 b = *(const u16x8*)&lds[orow][oc + 8];
    *(u16x8*)(d + (size_t)orow * R + oc)     = a;
    *(u16x8*)(d + (size_t)orow * R + oc + 8) = b;
}

// ---------------------------------------------------------------- gather+convert token rows -> xg bf16 [slot][D]
__global__ __launch_bounds__(256) void moe_gather_kernel(
    const float* __restrict__ x, const int* __restrict__ list_tok,
    const int* __restrict__ cnt, const int* __restrict__ offs,
    unsigned short* __restrict__ xg)
{
    int e  = blockIdx.x >> 8;
    int rb = blockIdx.x & 255;
    int n = cnt[e];
    int npad = (n + 63) & ~63;
    if (rb * 8 >= npad) return;
    int base = offs[e];
    int tid = threadIdx.x;
    #pragma unroll
    for (int i = 0; i < 4; ++i) {
        int u = tid + 256 * i;
        int r = u >> 7, cu = u & 127;
        int slot = rb * 8 + r;
        int tok = list_tok[e * T_TOK + slot];
        const float* sp = x + (size_t)tok * DDIM + cu * 8;
        float4 v0 = *(const float4*)(sp);
        float4 v1 = *(const float4*)(sp + 4);
        u16x8 t8;
        t8[0]=f2b(v0.x); t8[1]=f2b(v0.y); t8[2]=f2b(v0.z); t8[3]=f2b(v0.w);
        t8[4]=f2b(v1.x); t8[5]=f2b(v1.y); t8[6]=f2b(v1.z); t8[7]=f2b(v1.w);
        *(u16x8*)(xg + (size_t)(base + slot) * DDIM + cu * 8) = t8;
    }
}

// ---------------------------------------------------------------- expert up
// 1-phase (dbuf proven neutral, r7). Block tile 128 slots x 64 F; 4 waves 2x2,
// wave tile 64x32 per matrix -> acc 64 regs total -> 3 waves/SIMD.
// bid = [idx(10b) | xcd(3b)]; e = xcd; idx = mt*64 + fc, mt slowest.
__global__ __launch_bounds__(256, 3) void moe_up_kernel(
    const unsigned short* __restrict__ xg,
    const unsigned short* __restrict__ w1t, const unsigned short* __restrict__ w3t,
    const int* __restrict__ cnt, const int* __restrict__ offs,
    unsigned short* __restrict__ act)
{
    int e   = blockIdx.x & 7;
    int idx = blockIdx.x >> 3;      // 0..1023
    int mt  = idx >> 6;             // 0..15 (slowest -> active first)
    int fc  = idx & 63;             // 64-col F chunk
    int n = cnt[e];
    int npad = (n + 63) & ~63;
    if (mt * 128 >= npad) return;
    int rowBase  = offs[e] + mt * 128;
    int rowMax   = offs[e] + npad - 1;
    int rowLimit = offs[e] + npad;

    __shared__ unsigned short As [128 * 32];   // [row][k] linear
    __shared__ unsigned short B1s[64 * 32];    // [fcol][k] linear
    __shared__ unsigned short B2s[64 * 32];

    int tid = threadIdx.x;
    int lane = tid & 63, wv = tid >> 6;
    int c = lane & 15, g = lane >> 4;
    int wr = (wv >> 1) * 64, wc = (wv & 1) * 32;

    int srow = tid >> 2, skc = tid & 3;        // A: 64 rows x 4 kc per round, 2 rounds
    int r0 = min(rowBase + srow,      rowMax);
    int r1 = min(rowBase + 64 + srow, rowMax);
    const unsigned short* gA0 = xg + (size_t)r0 * DDIM + skc * 8;
    const unsigned short* gA1 = xg + (size_t)r1 * DDIM + skc * 8;
    size_t wb = (size_t)e * FDIM * DDIM + (size_t)(fc * 64 + srow) * DDIM + skc * 8;  // srow==col, skc==kc
    const unsigned short* gB1 = w1t + wb;
    const unsigned short* gB2 = w3t + wb;
    unsigned short* lA0 = As  + tid * 8;
    unsigned short* lA1 = As  + 2048 + tid * 8;
    unsigned short* lB1 = B1s + tid * 8;
    unsigned short* lB2 = B2s + tid * 8;

    f32x4 acc_h[4][2], acc_g[4][2];
    #pragma unroll
    for (int i = 0; i < 4; ++i)
        #pragma unroll
        for (int j = 0; j < 2; ++j) { acc_h[i][j] = (f32x4)(0.f); acc_g[i][j] = (f32x4)(0.f); }

    for (int k0 = 0; k0 < DDIM; k0 += 32) {
        gll16(gA0 + k0, lA0);
        gll16(gA1 + k0, lA1);
        gll16(gB1 + k0, lB1);
        gll16(gB2 + k0, lB2);
        __syncthreads();

        bf16x8 af[4];
        #pragma unroll
        for (int mi = 0; mi < 4; ++mi)
            af[mi] = *reinterpret_cast<const bf16x8*>(&As[(wr + mi * 16 + c) * 32 + g * 8]);
        #pragma unroll
        for (int ni = 0; ni < 2; ++ni) {
            bf16x8 b1 = *reinterpret_cast<const bf16x8*>(&B1s[(wc + ni * 16 + c) * 32 + g * 8]);
            bf16x8 b2 = *reinterpret_cast<const bf16x8*>(&B2s[(wc + ni * 16 + c) * 32 + g * 8]);
            #pragma unroll
            for (int mi = 0; mi < 4; ++mi) {
                acc_h[mi][ni] = __builtin_amdgcn_mfma_f32_16x16x32_bf16(af[mi], b1, acc_h[mi][ni], 0, 0, 0);
                acc_g[mi][ni] = __builtin_amdgcn_mfma_f32_16x16x32_bf16(af[mi], b2, acc_g[mi][ni], 0, 0, 0);
            }
        }
        __syncthreads();
    }

    #pragma unroll
    for (int mi = 0; mi < 4; ++mi) {
        int row = rowBase + wr + mi * 16 + 4 * g;
        if (row < rowLimit) {
            #pragma unroll
            for (int ni = 0; ni < 2; ++ni) {
                int col = fc * 64 + wc + ni * 16 + c;
                #pragma unroll
                for (int r = 0; r < 4; ++r) {
                    float h  = acc_h[mi][ni][r];
                    float gg = acc_g[mi][ni][r];
                    float a  = h / (1.f + __expf(-h)) * gg;
                    act[(size_t)(row + r) * FDIM + col] = f2b(a);
                }
            }
        }
    }
}

// ---------------------------------------------------------------- expert down
// 1-phase. Block tile 128 slots x 64 D; wave 64x32 -> acc 32 regs -> 4 waves/SIMD.
// split-K x2 (2048/split). bid = [idx(9b) | xcd(3b)]; idx = mt*32 + ks*16 + dc.
__global__ __launch_bounds__(256, 4) void moe_down_kernel(
    const unsigned short* __restrict__ act, const unsigned short* __restrict__ w2t,
    const int* __restrict__ cnt, const int* __restrict__ offs,
    const int* __restrict__ list_tok, const float* __restrict__ list_w,
    float* __restrict__ out)
{
    int e   = blockIdx.x & 7;
    int idx = blockIdx.x >> 3;      // 0..511
    int mt  = idx >> 5;             // 0..15, slowest
    int ks  = (idx >> 4) & 1;
    int dc  = idx & 15;
    int n = cnt[e];
    int npad = (n + 63) & ~63;
    if (mt * 128 >= npad) return;
    int rowBase = offs[e] + mt * 128;
    int rowMax  = offs[e] + npad - 1;

    __shared__ unsigned short As[128 * 32];
    __shared__ unsigned short Bs[64 * 32];

    int tid = threadIdx.x;
    int lane = tid & 63, wv = tid >> 6;
    int c = lane & 15, g = lane >> 4;
    int wr = (wv >> 1) * 64, wc = (wv & 1) * 32;

    int srow = tid >> 2, skc = tid & 3;
    int r0 = min(rowBase + srow,      rowMax);
    int r1 = min(rowBase + 64 + srow, rowMax);
    const unsigned short* gA0 = act + (size_t)r0 * FDIM + ks * 2048 + skc * 8;
    const unsigned short* gA1 = act + (size_t)r1 * FDIM + ks * 2048 + skc * 8;
    const unsigned short* gB  = w2t + (size_t)e * DDIM * FDIM
                                    + (size_t)(dc * 64 + srow) * FDIM + ks * 2048 + skc * 8;
    unsigned short* lA0 = As + tid * 8;
    unsigned short* lA1 = As + 2048 + tid * 8;
    unsigned short* lB  = Bs + tid * 8;

    f32x4 acc[4][2];
    #pragma unroll
    for (int i = 0; i < 4; ++i)
        #pragma unroll
        for (int j = 0; j < 2; ++j) acc[i][j] = (f32x4)(0.f);

    for (int k0 = 0; k0 < 2048; k0 += 32) {
        gll16(gA0 + k0, lA0);
        gll16(gA1 + k0, lA1);
        gll16(gB  + k0, lB);
        __syncthreads();

        bf16x8 af[4];
        #pragma unroll
        for (int mi = 0; mi < 4; ++mi)
            af[mi] = *reinterpret_cast<const bf16x8*>(&As[(wr + mi * 16 + c) * 32 + g * 8]);
        #pragma unroll
        for (int ni = 0; ni < 2; ++ni) {
            bf16x8 b = *reinterpret_cast<const bf16x8*>(&Bs[(wc + ni * 16 + c) * 32 + g * 8]);
            #pragma unroll
            for (int mi = 0; mi < 4; ++mi)
                acc[mi][ni] = __builtin_amdgcn_mfma_f32_16x16x32_bf16(af[mi], b, acc[mi][ni], 0, 0, 0);
        }
        __syncthreads();
    }

    #pragma unroll
    for (int mi = 0; mi < 4; ++mi) {
        #pragma unroll
        for (int r = 0; r < 4; ++r) {
            int s = mt * 128 + wr + mi * 16 + 4 * g + r;
            if (s < n) {
                int   tok = list_tok[e * T_TOK + s];
                float wt  = list_w [e * T_TOK + s];
                #pragma unroll
                for (int ni = 0; ni < 2; ++ni) {
                    int col = dc * 64 + wc + ni * 16 + c;
                    atomicAdd(&out[(size_t)tok * DDIM + col], wt * acc[mi][ni][r]);
                }
            }
        }
    }
}

// ================================================================ legacy fp32-weight path (ws too small)
__global__ __launch_bounds__(256, 3) void moe_up_legacy(
    const float* __restrict__ x, const float* __restrict__ w1, const float* __restrict__ w3,
    const int* __restrict__ cnt, const int* __restrict__ offs,
    const int* __restrict__ list_tok, unsigned short* __restrict__ act)
{
    const int NWG = NEXP * 32 * 32;
    int bid     = blockIdx.x;
    int logical = (bid & 7) * (NWG >> 3) + (bid >> 3);
    int tile = logical & 31;
    int fc   = (logical >> 5) & 31;
    int e    = logical >> 10;
    int n = cnt[e];
    if (tile * 64 >= n) return;

    __shared__ unsigned short As [64  * LDSP];
    __shared__ unsigned short B1s[FCW * LDSP];
    __shared__ unsigned short B2s[FCW * LDSP];

    int tid = threadIdx.x;
    int lane = tid & 63, wv = tid >> 6;
    int c = lane & 15, g = lane >> 4;
    int ar = tid >> 2, akq = tid & 3;
    int tok = list_tok[e * T_TOK + tile * 64 + ar];
    const float* xrow = x + (size_t)tok * DDIM + akq * 8;
    int bcol = tid & 127, bkh = tid >> 7;
    const size_t wbase = (size_t)e * DDIM * FDIM + (size_t)fc * FCW + bcol;
    const float* w1c = w1 + wbase;
    const float* w3c = w3 + wbase;

    f32x4 acc_h[4][2], acc_g[4][2];
    #pragma unroll
    for (int i = 0; i < 4; ++i)
        #pragma unroll
        for (int j = 0; j < 2; ++j) { acc_h[i][j] = (f32x4)(0.f); acc_g[i][j] = (f32x4)(0.f); }

    for (int k0 = 0; k0 < DDIM; k0 += 32) {
        {
            const float4 v0 = *(const float4*)(xrow + k0);
            const float4 v1 = *(const float4*)(xrow + k0 + 4);
            u16x8 t8;
            t8[0]=f2b(v0.x); t8[1]=f2b(v0.y); t8[2]=f2b(v0.z); t8[3]=f2b(v0.w);
            t8[4]=f2b(v1.x); t8[5]=f2b(v1.y); t8[6]=f2b(v1.z); t8[7]=f2b(v1.w);
            *reinterpret_cast<u16x8*>(&As[ar * LDSP + akq * 8]) = t8;
        }
        {
            int kb = k0 + bkh * 16;
            u16x8 t1a, t1b, t2a, t2b;
            #pragma unroll
            for (int j = 0; j < 8; ++j) {
                t1a[j] = f2b(w1c[(size_t)(kb + j)     * FDIM]);
                t1b[j] = f2b(w1c[(size_t)(kb + 8 + j) * FDIM]);
                t2a[j] = f2b(w3c[(size_t)(kb + j)     * FDIM]);
                t2b[j] = f2b(w3c[(size_t)(kb + 8 + j) * FDIM]);
            }
            *reinterpret_cast<u16x8*>(&B1s[bcol * LDSP + bkh * 16])     = t1a;
            *reinterpret_cast<u16x8*>(&B1s[bcol * LDSP + bkh * 16 + 8]) = t1b;
            *reinterpret_cast<u16x8*>(&B2s[bcol * LDSP + bkh * 16])     = t2a;
            *reinterpret_cast<u16x8*>(&B2s[bcol * LDSP + bkh * 16 + 8]) = t2b;
        }
        __syncthreads();
        bf16x8 af[4];
        #pragma unroll
        for (int mi = 0; mi < 4; ++mi)
            af[mi] = *reinterpret_cast<const bf16x8*>(&As[(mi * 16 + c) * LDSP + g * 8]);
        #pragma unroll
        for (int ni = 0; ni < 2; ++ni) {
            int col = wv * 32 + ni * 16 + c;
            bf16x8 b1 = *reinterpret_cast<const bf16x8*>(&B1s[col * LDSP + g * 8]);
            bf16x8 b2 = *reinterpret_cast<const bf16x8*>(&B2s[col * LDSP + g * 8]);
            #pragma unroll
            for (int mi = 0; mi < 4; ++mi) {
                acc_h[mi][ni] = __builtin_amdgcn_mfma_f32_16x16x32_bf16(af[mi], b1, acc_h[mi][ni], 0, 0, 0);
                acc_g[mi][ni] = __builtin_amdgcn_mfma_f32_16x16x32_bf16(af[mi], b2, acc_g[mi][ni], 0, 0, 0);
            }
        }
        __syncthreads();
    }
    int rowBase = offs[e] + tile * 64;
    #pragma unroll
    for (int mi = 0; mi < 4; ++mi)
        #pragma unroll
        for (int ni = 0; ni < 2; ++ni)
            #pragma unroll
            for (int r = 0; r < 4; ++r) {
                float h  = acc_h[mi][ni][r];
                float gg = acc_g[mi][ni][r];
                float a  = h / (1.f + __expf(-h)) * gg;
                int row = rowBase + mi * 16 + 4 * g + r;
                int col = fc * FCW + wv * 32 + ni * 16 + c;
                act[(size_t)row * FDIM + col] = f2b(a);
            }
}

__global__ __launch_bounds__(256, 3) void moe_down_legacy(
    const unsigned short* __restrict__ act, const float* __restrict__ w2,
    const int* __restrict__ cnt, const int* __restrict__ offs,
    const int* __restrict__ list_tok, const float* __restrict__ list_w,
    float* __restrict__ out)
{
    const int NWG = NEXP * 4 * 4 * 32;
    int bid     = blockIdx.x;
    int logical = (bid & 7) * (NWG >> 3) + (bid >> 3);
    int tile = logical & 31;
    int ks   = (logical >> 5) & 3;
    int dc   = (logical >> 7) & 3;
    int e    = logical >> 9;
    int n = cnt[e];
    if (tile * 64 >= n) return;

    __shared__ unsigned short As[64  * LDSP];
    __shared__ unsigned short Bs[256 * LDSP];
    int tid = threadIdx.x;
    int lane = tid & 63, wv = tid >> 6;
    int c = lane & 15, g = lane >> 4;
    int rowBase = offs[e] + tile * 64;
    int ar = tid >> 2, akq = tid & 3;
    const unsigned short* arow = act + (size_t)(rowBase + ar) * FDIM + ks * 1024 + akq * 8;
    const float* w2c = w2 + (size_t)e * FDIM * DDIM + (size_t)(ks * 1024) * DDIM + (size_t)dc * 256 + tid;

    f32x4 acc[4][4];
    #pragma unroll
    for (int i = 0; i < 4; ++i)
        #pragma unroll
        for (int j = 0; j < 4; ++j) acc[i][j] = (f32x4)(0.f);

    for (int k0 = 0; k0 < 1024; k0 += 32) {
        *reinterpret_cast<u16x8*>(&As[ar * LDSP + akq * 8]) = *reinterpret_cast<const u16x8*>(arow + k0);
        #pragma unroll
        for (int kk = 0; kk < 4; ++kk) {
            u16x8 t1;
            #pragma unroll
            for (int j = 0; j < 8; ++j)
                t1[j] = f2b(w2c[(size_t)(k0 + kk * 8 + j) * DDIM]);
            *reinterpret_cast<u16x8*>(&Bs[tid * LDSP + kk * 8]) = t1;
        }
        __syncthreads();
        bf16x8 af[4];
        #pragma unroll
        for (int mi = 0; mi < 4; ++mi)
            af[mi] = *reinterpret_cast<const bf16x8*>(&As[(mi * 16 + c) * LDSP + g * 8]);
        #pragma unroll
        for (int ni = 0; ni < 4; ++ni) {
            bf16x8 b = *reinterpret_cast<const bf16x8*>(&Bs[(wv * 64 + ni * 16 + c) * LDSP + g * 8]);
            #pragma unroll
            for (int mi = 0; mi < 4; ++mi)
                acc[mi][ni] = __builtin_amdgcn_mfma_f32_16x16x32_bf16(af[mi], b, acc[mi][ni], 0, 0, 0);
        }
        __syncthreads();
    }
    #pragma unroll
    for (int mi = 0; mi < 4; ++mi)
        #pragma unroll
        for (int r = 0; r < 4; ++r) {
            int s = tile * 64 + mi * 16 + 4 * g + r;
            if (s < n) {
                int   tok = list_tok[e * T_TOK + s];
                float wt  = list_w [e * T_TOK + s];
                #pragma unroll
                for (int ni = 0; ni < 4; ++ni) {
                    int col = dc * 256 + wv * 64 + ni * 16 + c;
                    atomicAdd(&out[(size_t)tok * DDIM + col], wt * acc[mi][ni][r]);
                }
            }
        }
}

// ---------------------------------------------------------------- launch
extern "C" void kernel_launch(void* const* d_in, const int* in_sizes, int n_in,
                              void* d_out, int out_size, void* d_ws, size_t ws_size,
                              hipStream_t stream) {
    const float* x      = (const float*)d_in[0];
    const float* gate_w = (const float*)d_in[1];
    const float* w1     = (const float*)d_in[2];
    const float* w2     = (const float*)d_in[3];
    const float* w3     = (const float*)d_in[4];
    float* out        = (float*)d_out;
    float* logits_out = out + (size_t)T_TOK * DDIM;

    char* ws = (char*)d_ws;
    int*   cnt      = (int*)  (ws);
    int*   offs     = (int*)  (ws + 64);
    int*   top_e    = (int*)  (ws + 1024);
    float* top_w    = (float*)(ws + 17408);
    int*   list_tok = (int*)  (ws + 33792);
    float* list_w   = (float*)(ws + 99328);

    hipMemsetAsync(cnt, 0, 64, stream);
    hipMemsetAsync(list_tok, 0, 131072, stream);   // list_tok + list_w
    hipMemsetAsync(out, 0, (size_t)T_TOK * DDIM * sizeof(float), stream);

    moe_router_kernel <<<T_TOK / 4,   256, 0, stream>>>(x, gate_w, logits_out, top_e, top_w);
    moe_scatter_kernel<<<T_TOK / 256, 256, 0, stream>>>(top_e, top_w, cnt, list_tok, list_w);
    moe_prefix_kernel <<<1, 64, 0, stream>>>(cnt, offs);

    const size_t MB = 1u << 20;
    const size_t NEED = 241 * MB;
    if (ws_size >= NEED) {
        unsigned short* xg  = (unsigned short*)(ws + 1   * MB);   //  9.44 MB
        unsigned short* act = (unsigned short*)(ws + 11  * MB);   // 37.75 MB
        unsigned short* w1t = (unsigned short*)(ws + 49  * MB);   // 64 MB  [E][F][D]
        unsigned short* w3t = (unsigned short*)(ws + 113 * MB);   // 64 MB  [E][F][D]
        unsigned short* w2t = (unsigned short*)(ws + 177 * MB);   // 64 MB  [E][D][F]

        moe_gather_kernel<<<NEXP * 256, 256, 0, stream>>>(x, list_tok, cnt, offs, xg);
        transpose_cvt2_kernel<<<NEXP * 16 * 64, 256, 0, stream>>>(w1, w1t, w3, w3t, DDIM, FDIM);
        transpose_cvt_kernel <<<NEXP * 64 * 16, 256, 0, stream>>>(w2, w2t, FDIM, DDIM);

        moe_up_kernel   <<<NEXP * 16 * 64, 256, 0, stream>>>(xg, w1t, w3t, cnt, offs, act);
        moe_down_kernel <<<NEXP * 16 * 32, 256, 0, stream>>>(act, w2t, cnt, offs, list_tok, list_w, out);
    } else {
        unsigned short* act = (unsigned short*)(ws + 164864);
        moe_up_legacy   <<<NEXP * 32 * 32,    256, 0, stream>>>(x, w1, w3, cnt, offs, list_tok, act);
        moe_down_legacy <<<NEXP * 4 * 4 * 32, 256, 0, stream>>>(act, w2, cnt, offs, list_tok, list_w, out);
    }
}